// Round 3
// baseline (391.547 us; speedup 1.0000x reference)
//
#include <hip/hip_runtime.h>

// QRegulariser: theta = hidden[B,H] @ W[Q,H]^T + b;  out = mean(1 - prod_q cos^2(theta_q/2))
// B=65536, H=1024, Q=8.  HBM-bound: stream 256 MB of hidden exactly once (41 us floor).
//
// R2 design: wave-private, barrier-free hot loop.  Each wave owns 64 rows x
// a 256-float h-segment, double-buffers 8.32 KB LDS tiles via
// global_load_lds width=16 (8 insts/chunk, each = 8 rows x 128 B full cache
// lines).  No __syncthreads until the epilogue -> no vmcnt(0) barrier drains;
// waits are wave-local.  lane==row in compute -> W offsets wave-uniform
// (scalar s_loads).  1040 B inst padding makes ds_read_b128 a bank Latin
// square (uniform 8 dwords/bank = conflict-free).

#define HDIM 1024
#define QN 8
#define RPB 64            // rows per block (and per wave)
#define SEG 256           // h-floats per wave segment (4 waves cover H=1024)
#define CHUNK 32          // h-floats per row per chunk
#define NCHUNK 8          // SEG / CHUNK
#define INST_PAD 1040     // LDS bytes per 1 KB DMA inst-block (16 B pad)
#define BUF_BYTES (8 * INST_PAD)    // 8320 B per chunk buffer
#define WAVE_BYTES (2 * BUF_BYTES)  // double-buffered

__global__ __launch_bounds__(256, 2)
void qreg_kernel(const float* __restrict__ hidden,
                 const float* __restrict__ W,
                 const float* __restrict__ bias,
                 float* __restrict__ out) {
    __shared__ __align__(16) char lds[4 * WAVE_BYTES]; // 66560 B -> 2 blocks/CU

    const int tid  = threadIdx.x;
    const int lane = tid & 63;
    const int w    = __builtin_amdgcn_readfirstlane(tid >> 6); // wave id 0..3
    const size_t row_base = (size_t)blockIdx.x * RPB;

    const int r = lane & 7;   // row within an inst's 8-row group
    const int s = lane >> 3;  // 16 B slot within the row's 128 B chunk-slice

    char* wlds = lds + w * WAVE_BYTES;
    const float* gbase = hidden + (row_base + r) * HDIM + w * SEG + s * 4;

    // ---- prologue: DMA chunk 0 into buffer 0 ----
#pragma unroll
    for (int i = 0; i < 8; ++i) {
        __builtin_amdgcn_global_load_lds(
            (const __attribute__((address_space(1))) void*)(gbase + (size_t)(i * 8) * HDIM),
            (__attribute__((address_space(3))) void*)(wlds + i * INST_PAD),
            16, 0, 0);
    }

    float acc[QN];
#pragma unroll
    for (int q = 0; q < QN; ++q) acc[q] = 0.f;

#pragma unroll
    for (int c = 0; c < NCHUNK; ++c) {
        const int b = c & 1;

        // read this chunk's 32 floats for row `lane` (compiler inserts the
        // wave-local vmcnt wait for this buffer's DMAs)
        const char* rowb = wlds + b * BUF_BYTES + (lane >> 3) * INST_PAD + (lane & 7) * 16;
        float4 x[8];
#pragma unroll
        for (int j = 0; j < 8; ++j)
            x[j] = *reinterpret_cast<const float4*>(rowb + j * 128);

        // prefetch next chunk into the other buffer (no barrier in the way)
        if (c + 1 < NCHUNK) {
#pragma unroll
            for (int i = 0; i < 8; ++i) {
                __builtin_amdgcn_global_load_lds(
                    (const __attribute__((address_space(1))) void*)(gbase + (size_t)(i * 8) * HDIM + (c + 1) * CHUNK),
                    (__attribute__((address_space(3))) void*)(wlds + (b ^ 1) * BUF_BYTES + i * INST_PAD),
                    16, 0, 0);
            }
        }

        // FMAs: W offsets wave-uniform -> scalar loads
        const float* wseg = W + w * SEG + c * CHUNK;
#pragma unroll
        for (int q = 0; q < QN; ++q) {
            const float* wq = wseg + q * HDIM;
            float a = acc[q];
#pragma unroll
            for (int j = 0; j < 8; ++j) {
                a += x[j].x * wq[j * 4 + 0] + x[j].y * wq[j * 4 + 1]
                   + x[j].z * wq[j * 4 + 2] + x[j].w * wq[j * 4 + 3];
            }
            acc[q] = a;
        }
    }

    // ---- epilogue: combine the 4 wave-partials per row ----
    __syncthreads(); // all waves done with their buffers before reuse
    float* part = (float*)lds; // part[w*64+lane][8] = 8 KB
#pragma unroll
    for (int q = 0; q < QN; ++q)
        part[(w * RPB + lane) * 8 + q] = acc[q];
    __syncthreads();

    if (tid < 64) {
        float th[QN];
#pragma unroll
        for (int q = 0; q < QN; ++q) th[q] = bias[q];
#pragma unroll
        for (int ww = 0; ww < 4; ++ww)
#pragma unroll
            for (int q = 0; q < QN; ++q)
                th[q] += part[(ww * RPB + tid) * 8 + q];

        float p0 = 1.f;
#pragma unroll
        for (int q = 0; q < QN; ++q) {
            float cc = __cosf(0.5f * th[q]);
            p0 *= cc * cc;
        }
        float contrib = 1.f - p0;
#pragma unroll
        for (int off = 32; off > 0; off >>= 1)
            contrib += __shfl_down(contrib, off);
        if (tid == 0)
            atomicAdd(out, contrib * (1.0f / 65536.0f));
    }
}

extern "C" void kernel_launch(void* const* d_in, const int* in_sizes, int n_in,
                              void* d_out, int out_size, void* d_ws, size_t ws_size,
                              hipStream_t stream) {
    const float* hidden = (const float*)d_in[0];
    const float* W      = (const float*)d_in[1];
    const float* bias   = (const float*)d_in[2];
    float* out          = (float*)d_out;

    hipMemsetAsync(out, 0, sizeof(float), stream);
    qreg_kernel<<<65536 / RPB, 256, 0, stream>>>(hidden, W, bias, out);
}